// Round 7
// baseline (206.437 us; speedup 1.0000x reference)
//
#include <hip/hip_runtime.h>
#include <stdint.h>

// EdgeNetwork, round 7: value-carrying bins (scatter on WRITE, stream on READ).
//   out[a] = K-contraction of S_a,  S_a = sum_{e:dst=a} bond_e (x) neigh_e.
// r6 lesson: atom_kernel was latency-bound walking random 64B bond lines
// (~900cyc each, 647 GB/s). Now bin_kernel packs {bond,neigh} as bf16 into ONE
// 64B line per edge (scattered stores = fire-and-forget); atom_kernel streams
// contiguous entries with no gathers/shfls. Kt staged dest-ordered + pad 17.
// Fallback chain by ws_size: bf16-value bins (82MB) -> r6 id bins -> atomic.

constexpr int DIM  = 16;
constexpr int CAP  = 64;     // slots/atom; P(deg>64) ~1e-8 at Poisson(32)
constexpr int CSTR = 4;      // counts stride (ints): 16B apart
constexpr int OFLOW_CAP = 65536;

__device__ __forceinline__ uint32_t pack2(float lo, float hi) {
    return __builtin_amdgcn_perm(__float_as_uint(hi), __float_as_uint(lo), 0x07060302u);
}
__device__ __forceinline__ float blo(uint32_t u) { return __uint_as_float(u << 16); }
__device__ __forceinline__ float bhi(uint32_t u) { return __uint_as_float(u & 0xFFFF0000u); }

// ---- K1: bin values. Entry = 64B: bond[16] bf16 | neigh[16] bf16.
__global__ __launch_bounds__(256) void bin_val_kernel(
    const float* __restrict__ atom, const float* __restrict__ bond,
    const int* __restrict__ pair, int* __restrict__ counts,
    int* __restrict__ oflow_cnt, int* __restrict__ oflow,
    uint16_t* __restrict__ bins, int n_edges)
{
    int e = blockIdx.x * blockDim.x + threadIdx.x;
    if (e >= n_edges) return;
    int2 pr = ((const int2*)pair)[e];                       // x=dst, y=src
    const float4* bp = (const float4*)(bond + (size_t)e * DIM);   // coalesced
    float4 b0 = bp[0], b1 = bp[1], b2 = bp[2], b3 = bp[3];
    const float4* ap = (const float4*)(atom + (size_t)pr.y * DIM); // L2 gather
    float4 n0 = ap[0], n1 = ap[1], n2 = ap[2], n3 = ap[3];

    int r = atomicAdd(&counts[pr.x * CSTR], 1);
    if (r < CAP) {
        uint32_t* dst = (uint32_t*)(bins + ((size_t)pr.x * CAP + r) * 32);
        uint4 w;
        w.x = pack2(b0.x, b0.y); w.y = pack2(b0.z, b0.w);
        w.z = pack2(b1.x, b1.y); w.w = pack2(b1.z, b1.w);
        ((uint4*)dst)[0] = w;
        w.x = pack2(b2.x, b2.y); w.y = pack2(b2.z, b2.w);
        w.z = pack2(b3.x, b3.y); w.w = pack2(b3.z, b3.w);
        ((uint4*)dst)[1] = w;
        w.x = pack2(n0.x, n0.y); w.y = pack2(n0.z, n0.w);
        w.z = pack2(n1.x, n1.y); w.w = pack2(n1.z, n1.w);
        ((uint4*)dst)[2] = w;
        w.x = pack2(n2.x, n2.y); w.y = pack2(n2.z, n2.w);
        w.z = pack2(n3.x, n3.y); w.w = pack2(n3.z, n3.w);
        ((uint4*)dst)[3] = w;
    } else {
        int oi = atomicAdd(oflow_cnt, 1);
        if (oi < OFLOW_CAP) oflow[oi] = e;
    }
}

// ---- K2: one wave per atom; stream contiguous entries, rank-1 update S,
// then 68-step dot with K^T (+bias) from LDS.
__global__ __launch_bounds__(256) void atom_val_kernel(
    const uint16_t* __restrict__ bins, const float* __restrict__ kern,
    const float* __restrict__ bias, const int* __restrict__ counts,
    float* __restrict__ out, int n_atoms)
{
    __shared__ float Kt[272 * 17];    // Kt[o*17+i], pad 17 kills staging conflicts
    __shared__ float Sl[4][272];      // per-wave S(256) + nsum(16)

    const int tid  = threadIdx.x;
    const int lane = tid & 63;
    const int w    = tid >> 6;

    // dest-ordered staging: d -> (o=d>>4, i=d&15); consecutive lanes hit
    // consecutive LDS words (bank-clean); kern source is L2-resident.
    for (int d = tid; d < 272 * 16; d += 256) {
        const int o = d >> 4, i = d & 15;
        float v;
        if (o < 256) v = kern[(o >> 4) * 256 + i * 16 + (o & 15)];
        else         v = bias[i * 16 + (o - 256)];
        Kt[o * 17 + i] = v;
    }
    __syncthreads();

    const int  a      = blockIdx.x * 4 + w;
    const bool active = (a < n_atoms);

    const int k4 = lane >> 2;          // S row (bond feature)
    const int j4 = (lane & 3) * 4;     // S col quarter

    if (active) {
        const int deg = min(counts[a * CSTR], CAP);
        const uint16_t* base = bins + (size_t)a * CAP * 32;

        float4 S4  = {0.f, 0.f, 0.f, 0.f};
        float4 ns4 = {0.f, 0.f, 0.f, 0.f};
#pragma unroll 4
        for (int t = 0; t < deg; ++t) {
            const uint16_t* ent = base + t * 32;      // sequential 64B lines
            const float bv = blo((uint32_t)ent[k4]);
            uint2 nv = *(const uint2*)(ent + 16 + j4);
            const float nx = blo(nv.x), ny = bhi(nv.x);
            const float nz = blo(nv.y), nw = bhi(nv.y);
            S4.x = fmaf(bv, nx, S4.x);
            S4.y = fmaf(bv, ny, S4.y);
            S4.z = fmaf(bv, nz, S4.z);
            S4.w = fmaf(bv, nw, S4.w);
            if (lane < 4) { ns4.x += nx; ns4.y += ny; ns4.z += nz; ns4.w += nw; }
        }
        *(float4*)&Sl[w][k4 * 16 + j4] = S4;
        if (lane < 4) *(float4*)&Sl[w][256 + j4] = ns4;
    }
    __syncthreads();   // uniform

    if (active) {
        const int i = lane & 15, p = lane >> 4;
        float acc = 0.f;
#pragma unroll 4
        for (int q = 0; q < 68; ++q) {
            const int o = p + q * 4;
            acc = fmaf(Kt[o * 17 + i], Sl[w][o], acc);
        }
        acc += __shfl_xor(acc, 16, 64);
        acc += __shfl_xor(acc, 32, 64);
        if (lane < 16) out[(size_t)a * DIM + i] = acc;
    }
}

// ================= fallback B: r6 id-bins (ws-lean, verified 181us) =========
__global__ __launch_bounds__(256) void bin_id_kernel(
    const int* __restrict__ pair, int* __restrict__ counts,
    int* __restrict__ oflow_cnt, int* __restrict__ oflow,
    int2* __restrict__ bins, int n_edges)
{
    int e = blockIdx.x * blockDim.x + threadIdx.x;
    if (e >= n_edges) return;
    int2 pr = ((const int2*)pair)[e];
    int r = atomicAdd(&counts[pr.x * CSTR], 1);
    if (r < CAP) bins[pr.x * CAP + r] = make_int2(e, pr.y);
    else { int oi = atomicAdd(oflow_cnt, 1); if (oi < OFLOW_CAP) oflow[oi] = e; }
}

__global__ __launch_bounds__(256) void atom_id_kernel(
    const float* __restrict__ atom, const float* __restrict__ bond,
    const float* __restrict__ kern, const float* __restrict__ bias,
    const int* __restrict__ counts, const int2* __restrict__ bins,
    float* __restrict__ out, int n_atoms)
{
    __shared__ float Kt[272 * 17];
    __shared__ float Sl[4][272];
    const int tid = threadIdx.x, lane = tid & 63, w = tid >> 6;
    for (int d = tid; d < 272 * 16; d += 256) {
        const int o = d >> 4, i = d & 15;
        float v;
        if (o < 256) v = kern[(o >> 4) * 256 + i * 16 + (o & 15)];
        else         v = bias[i * 16 + (o - 256)];
        Kt[o * 17 + i] = v;
    }
    __syncthreads();
    const int a = blockIdx.x * 4 + w;
    const bool active = (a < n_atoms);
    const int k4 = lane >> 2, j4 = (lane & 3) * 4;
    if (active) {
        const int deg = min(counts[a * CSTR], CAP);
        int be = 0, bs = 0;
        if (lane < deg) { int2 b = bins[a * CAP + lane]; be = b.x; bs = b.y; }
        float4 S4 = {0.f,0.f,0.f,0.f}, ns4 = {0.f,0.f,0.f,0.f};
#pragma unroll 4
        for (int t = 0; t < deg; ++t) {
            const int e = __shfl(be, t, 64), src = __shfl(bs, t, 64);
            const float bv = bond[(size_t)e * DIM + k4];
            const float4 nv = *(const float4*)(atom + (size_t)src * DIM + j4);
            S4.x = fmaf(bv, nv.x, S4.x); S4.y = fmaf(bv, nv.y, S4.y);
            S4.z = fmaf(bv, nv.z, S4.z); S4.w = fmaf(bv, nv.w, S4.w);
            if (lane < 4) { ns4.x += nv.x; ns4.y += nv.y; ns4.z += nv.z; ns4.w += nv.w; }
        }
        *(float4*)&Sl[w][k4 * 16 + j4] = S4;
        if (lane < 4) *(float4*)&Sl[w][256 + j4] = ns4;
    }
    __syncthreads();
    if (active) {
        const int i = lane & 15, p = lane >> 4;
        float acc = 0.f;
#pragma unroll 4
        for (int q = 0; q < 68; ++q) { const int o = p + q * 4;
            acc = fmaf(Kt[o * 17 + i], Sl[w][o], acc); }
        acc += __shfl_xor(acc, 16, 64);
        acc += __shfl_xor(acc, 32, 64);
        if (lane < 16) out[(size_t)a * DIM + i] = acc;
    }
}

// ---- overflow fix-up (normally empty): exact f32 per edge, runs after out
__global__ __launch_bounds__(256) void oflow_kernel(
    const float* __restrict__ atom, const float* __restrict__ bond,
    const int*   __restrict__ pair, const float* __restrict__ kern,
    const float* __restrict__ bias,
    const int* __restrict__ oflow_cnt, const int* __restrict__ oflow,
    float* __restrict__ out, int n_edges)
{
    int n = min(*oflow_cnt, OFLOW_CAP);
    for (int idx = blockIdx.x * blockDim.x + threadIdx.x; idx < n;
         idx += gridDim.x * blockDim.x) {
        int e = oflow[idx];
        int dst = pair[2 * e + 0], src = pair[2 * e + 1];
        float neigh[DIM], bnd[DIM], acc[DIM];
        for (int q = 0; q < DIM; ++q) neigh[q] = atom[(size_t)src * DIM + q];
        for (int q = 0; q < DIM; ++q) bnd[q]   = bond[(size_t)e * DIM + q];
#pragma unroll
        for (int ii = 0; ii < DIM; ++ii) {
            float d = 0.f;
#pragma unroll
            for (int j = 0; j < DIM; ++j) d = fmaf(bias[ii * DIM + j], neigh[j], d);
            acc[ii] = d;
        }
#pragma unroll 1
        for (int k = 0; k < DIM; ++k) {
            const float bk = bnd[k];
            const float* Kr = kern + k * 256;
#pragma unroll
            for (int ii = 0; ii < DIM; ++ii) {
                float d = 0.f;
#pragma unroll
                for (int j = 0; j < DIM; ++j) d = fmaf(Kr[ii * DIM + j], neigh[j], d);
                acc[ii] = fmaf(bk, d, acc[ii]);
            }
        }
#pragma unroll
        for (int ii = 0; ii < DIM; ++ii)
            atomicAdd(&out[(size_t)dst * DIM + ii], acc[ii]);
    }
}

// ---- fallback C: plain atomic scatter
__global__ __launch_bounds__(256) void edge_atomic_kernel(
    const float* __restrict__ atom, const float* __restrict__ bond,
    const int*   __restrict__ pair, const float* __restrict__ kern,
    const float* __restrict__ bias, float* __restrict__ out, int n_edges)
{
    int e = blockIdx.x * blockDim.x + threadIdx.x;
    if (e >= n_edges) return;
    int dst = pair[2 * e + 0], src = pair[2 * e + 1];
    float neigh[DIM], bnd[DIM], acc[DIM];
    for (int q = 0; q < DIM; ++q) neigh[q] = atom[(size_t)src * DIM + q];
    for (int q = 0; q < DIM; ++q) bnd[q]   = bond[(size_t)e * DIM + q];
#pragma unroll
    for (int i = 0; i < DIM; ++i) {
        float d = 0.f;
#pragma unroll
        for (int j = 0; j < DIM; ++j) d = fmaf(bias[i * DIM + j], neigh[j], d);
        acc[i] = d;
    }
#pragma unroll 1
    for (int k = 0; k < DIM; ++k) {
        const float bk = bnd[k];
        const float* Kr = kern + k * 256;
#pragma unroll
        for (int i = 0; i < DIM; ++i) {
            float d = 0.f;
#pragma unroll
            for (int j = 0; j < DIM; ++j) d = fmaf(Kr[i * DIM + j], neigh[j], d);
            acc[i] = fmaf(bk, d, acc[i]);
        }
    }
#pragma unroll
    for (int i = 0; i < DIM; ++i) atomicAdd(&out[(size_t)dst * DIM + i], acc[i]);
}

extern "C" void kernel_launch(void* const* d_in, const int* in_sizes, int n_in,
                              void* d_out, int out_size, void* d_ws, size_t ws_size,
                              hipStream_t stream)
{
    const float* atom = (const float*)d_in[0];
    const float* bond = (const float*)d_in[1];
    const int*   pair = (const int*)d_in[2];
    const float* kern = (const float*)d_in[3];
    const float* bias = (const float*)d_in[4];
    float*       out  = (float*)d_out;

    const int n_edges = in_sizes[1] / DIM;   // 640000
    const int n_atoms = in_sizes[0] / DIM;   // 20000
    const int threads = 256;
    const int eblocks = (n_edges + threads - 1) / threads;
    const int ablocks = (n_atoms + 3) / 4;

    size_t counts_off = 0;
    size_t ocnt_off   = (size_t)n_atoms * CSTR * sizeof(int);
    size_t oflow_off  = ocnt_off + sizeof(int);
    size_t bins_off   = (oflow_off + (size_t)OFLOW_CAP * sizeof(int) + 63) & ~(size_t)63;
    size_t need_val   = bins_off + (size_t)n_atoms * CAP * 64;            // bf16 bins
    size_t need_id    = bins_off + (size_t)n_atoms * CAP * sizeof(int2);  // id bins

    if (ws_size >= need_id) {
        int* counts    = (int*)((char*)d_ws + counts_off);
        int* oflow_cnt = (int*)((char*)d_ws + ocnt_off);
        int* oflow     = (int*)((char*)d_ws + oflow_off);

        hipMemsetAsync(counts, 0,
                       (size_t)n_atoms * CSTR * sizeof(int) + sizeof(int), stream);

        if (ws_size >= need_val) {
            uint16_t* bins = (uint16_t*)((char*)d_ws + bins_off);
            bin_val_kernel<<<eblocks, threads, 0, stream>>>(
                atom, bond, pair, counts, oflow_cnt, oflow, bins, n_edges);
            atom_val_kernel<<<ablocks, threads, 0, stream>>>(
                bins, kern, bias, counts, out, n_atoms);
        } else {
            int2* bins = (int2*)((char*)d_ws + bins_off);
            bin_id_kernel<<<eblocks, threads, 0, stream>>>(
                pair, counts, oflow_cnt, oflow, bins, n_edges);
            atom_id_kernel<<<ablocks, threads, 0, stream>>>(
                atom, bond, kern, bias, counts, bins, out, n_atoms);
        }
        oflow_kernel<<<8, threads, 0, stream>>>(
            atom, bond, pair, kern, bias, oflow_cnt, oflow, out, n_edges);
    } else {
        hipMemsetAsync(out, 0, (size_t)out_size * sizeof(float), stream);
        edge_atomic_kernel<<<eblocks, threads, 0, stream>>>(
            atom, bond, pair, kern, bias, out, n_edges);
    }
}